// Round 2
// baseline (337.143 us; speedup 1.0000x reference)
//
#include <hip/hip_runtime.h>

// Problem constants (fixed by setup_inputs)
#define B_SZ   8192
#define CH     5120          // C*H = 20*256
#define CH4    1280          // CH / 4 (float4 columns per row)
#define K_LAB  10
#define EPS    1e-8f
#define FLTMAX 3.402823466e38f

// Tiling: 128 row-chunks x 4 col-chunks = 512 blocks (2 per CU)
#define RC_N   128
#define ROWS   64            // RC_N*ROWS == B_SZ
#define CC_N   4
#define CCW    320           // CC_N*CCW == CH4
#define NT1    320           // 5 waves
#define NBLK   (RC_N * CC_N)            // 512
#define NFOLD  (K_LAB * CC_N)           // 40 folder blocks (k, cc)
#define RCSTRIDE (K_LAB * CC_N * CCW)   // 12800 float4 per row-chunk in P_sum

// loss = sum_{k: n_k>0} (SSQ_k - ||S_k||^2/n_k + n_k*CH*eps^2) / (n_k*CH)
// (2*eps cross-term cancels exactly: sum_{b in k}(z_b - mu_k) == 0)

__device__ __forceinline__ float4 sanitize(float4 v) {
    v.x = (v.x == v.x) ? fminf(fmaxf(v.x, -FLTMAX), FLTMAX) : 0.f;
    v.y = (v.y == v.y) ? fminf(fmaxf(v.y, -FLTMAX), FLTMAX) : 0.f;
    v.z = (v.z == v.z) ? fminf(fmaxf(v.z, -FLTMAX), FLTMAX) : 0.f;
    v.w = (v.w == v.w) ? fminf(fmaxf(v.w, -FLTMAX), FLTMAX) : 0.f;
    return v;
}

// Single fused kernel: streaming partial pass + ticket-gated fold + finalize.
// Deadlock safety: only the LAST NFOLD blocks (by ticket) spin; all earlier
// blocks exit and free CU slots, and 40 spinners << 256+ concurrent capacity,
// so unscheduled blocks always make progress.
__global__ __launch_bounds__(NT1, 3) void codi_fused(
    const float4* __restrict__ z4, const int* __restrict__ labels,
    float4* __restrict__ P_sum, float* __restrict__ P_ssq,
    int* __restrict__ P_cnt, float* __restrict__ pn,
    float* __restrict__ ssqk, float* __restrict__ cntk,
    int* __restrict__ done, float* __restrict__ out)
{
    const int tid  = threadIdx.x;
    const int lane = tid & 63, wid = tid >> 6;
    const int rc   = blockIdx.x >> 2;    // row-chunk
    const int cc   = blockIdx.x & 3;     // col-chunk

    __shared__ int   lab_s[ROWS];
    __shared__ float wssq[5][K_LAB];
    __shared__ float red_q[5], red_s[5];
    __shared__ int   red_n[5];
    __shared__ int   tkt;

    // ---------------- phase 1: stream z, predicated per-label accumulation
    if (tid < ROWS) lab_s[tid] = labels[rc * ROWS + tid];
    __syncthreads();

    float4 sum[K_LAB];
    float  ssq[K_LAB];
    #pragma unroll
    for (int k = 0; k < K_LAB; ++k) {
        sum[k] = make_float4(0.f, 0.f, 0.f, 0.f);
        ssq[k] = 0.f;
    }

    const float4* zp = z4 + (size_t)rc * ROWS * CH4 + cc * CCW + tid;
    for (int r = 0; r < ROWS; r += 8) {
        float4 v[8];
        #pragma unroll
        for (int u = 0; u < 8; ++u) v[u] = zp[(size_t)(r + u) * CH4];

        #pragma unroll
        for (int u = 0; u < 8; ++u) {
            const int lab = __builtin_amdgcn_readfirstlane(lab_s[r + u]);
            float4 t = sanitize(v[u]);
            float  q = fmaf(t.x, t.x, fmaf(t.y, t.y, fmaf(t.z, t.z, t.w * t.w)));
            #pragma unroll
            for (int k = 0; k < K_LAB; ++k) {
                const float w = (lab == k) ? 1.f : 0.f;   // scalar operand
                sum[k].x = fmaf(t.x, w, sum[k].x);
                sum[k].y = fmaf(t.y, w, sum[k].y);
                sum[k].z = fmaf(t.z, w, sum[k].z);
                sum[k].w = fmaf(t.w, w, sum[k].w);
                ssq[k]   = fmaf(q,   w, ssq[k]);
            }
        }
    }

    // per-label partial row-sums: 10 x 5 KB coalesced float4 stores
    #pragma unroll
    for (int k = 0; k < K_LAB; ++k)
        P_sum[(((size_t)rc * K_LAB + k) * CC_N + cc) * CCW + tid] = sum[k];

    // block-reduce ssq[k] -> P_ssq[(rc*4+cc)*10 + k]
    #pragma unroll
    for (int k = 0; k < K_LAB; ++k) {
        float s = ssq[k];
        #pragma unroll
        for (int o = 32; o > 0; o >>= 1) s += __shfl_down(s, o, 64);
        if (lane == 0) wssq[wid][k] = s;
    }
    __syncthreads();
    if (tid < K_LAB)
        P_ssq[(rc * CC_N + cc) * K_LAB + tid] =
            wssq[0][tid] + wssq[1][tid] + wssq[2][tid] + wssq[3][tid] + wssq[4][tid];

    // per-chunk label counts (one writer: cc==0, wave 0, 10 ballots)
    if (cc == 0 && tid < 64) {
        const int lab = lab_s[tid];
        #pragma unroll
        for (int k = 0; k < K_LAB; ++k) {
            unsigned long long m = __ballot(lab == k);
            if (tid == k) P_cnt[rc * K_LAB + k] = __popcll(m);
        }
    }

    // ---------------- ticket: release writes, take a ticket
    __threadfence();                     // release: wbl2 before the increment
    if (tid == 0) tkt = atomicAdd(done, 1);
    __syncthreads();
    const int t1 = tkt;
    if (t1 < NBLK - NFOLD) return;       // early finishers free their slots

    // ---------------- folder blocks: wait for all 512, then fold
    if (tid == 0) {
        while (__hip_atomic_load(done, __ATOMIC_RELAXED,
                                 __HIP_MEMORY_SCOPE_AGENT) < NBLK)
            __builtin_amdgcn_s_sleep(8);
    }
    __syncthreads();
    __threadfence();                     // acquire: invalidate stale L1/L2

    const int fid = t1 - (NBLK - NFOLD); // 0..39
    const int fk  = fid >> 2, fcc = fid & 3;

    // ||S_k||^2 partial over this (k, cc): 320 cols, 128 rc each
    const float4* p = P_sum + ((size_t)fk * CC_N + fcc) * CCW + tid;
    float4 s4 = make_float4(0.f, 0.f, 0.f, 0.f);
    #pragma unroll 16
    for (int r2 = 0; r2 < RC_N; ++r2) {
        float4 v = p[(size_t)r2 * RCSTRIDE];
        s4.x += v.x; s4.y += v.y; s4.z += v.z; s4.w += v.w;
    }
    float q = fmaf(s4.x, s4.x, fmaf(s4.y, s4.y, fmaf(s4.z, s4.z, s4.w * s4.w)));
    #pragma unroll
    for (int o = 32; o > 0; o >>= 1) q += __shfl_down(q, o, 64);

    // SSQ_k and n_k folds (computed by all folders, stored by fcc==0)
    float s2 = P_ssq[tid * K_LAB + fk]
             + ((tid < 192) ? P_ssq[(tid + 320) * K_LAB + fk] : 0.f);
    #pragma unroll
    for (int o = 32; o > 0; o >>= 1) s2 += __shfl_down(s2, o, 64);
    int n = (tid < RC_N) ? P_cnt[tid * K_LAB + fk] : 0;
    #pragma unroll
    for (int o = 32; o > 0; o >>= 1) n += __shfl_down(n, o, 64);

    if (lane == 0) { red_q[wid] = q; red_s[wid] = s2; red_n[wid] = n; }
    __syncthreads();
    if (tid == 0) {
        pn[fid] = red_q[0] + red_q[1] + red_q[2] + red_q[3] + red_q[4];
        if (fcc == 0) {
            ssqk[fk] = red_s[0] + red_s[1] + red_s[2] + red_s[3] + red_s[4];
            cntk[fk] = (float)(red_n[0] + red_n[1] + red_n[2] + red_n[3] + red_n[4]);
        }
    }

    // ---------------- finalize: last folder computes the loss
    __threadfence();
    __syncthreads();                     // safe reuse of tkt
    if (tid == 0) tkt = atomicAdd(done, 1);   // tickets 512..551
    __syncthreads();
    if (tkt == NBLK + NFOLD - 1 && tid < 64) {
        float np4 = (tid < NFOLD) ? atomicAdd(&pn[tid], 0.f) : 0.f;   // coherent
        np4 += __shfl_down(np4, 2, 64);
        np4 += __shfl_down(np4, 1, 64);   // lane 4k holds sum over cc
        float s2v = (tid < K_LAB) ? atomicAdd(&ssqk[tid], 0.f) : 0.f;
        float nnv = (tid < K_LAB) ? atomicAdd(&cntk[tid], 0.f) : 0.f;
        float acc = 0.f;
        for (int k = 0; k < K_LAB; ++k) {
            float np = __shfl(np4, 4 * k, 64);
            float sk = __shfl(s2v, k, 64);
            float nk = __shfl(nnv, k, 64);
            if (nk > 0.f) {
                float sse = sk - np / nk + nk * (float)CH * (EPS * EPS);
                float mse = sse / (nk * (float)CH);
                if (mse == mse) acc += mse;    // nan_to_num(mse_k)
            }
        }
        if (tid == 0) out[0] = acc;
    }
}

// ---------------------------------------------------------------------------
extern "C" void kernel_launch(void* const* d_in, const int* in_sizes, int n_in,
                              void* d_out, int out_size, void* d_ws, size_t ws_size,
                              hipStream_t stream) {
    const float4* z4     = (const float4*)d_in[0];
    const int*    labels = (const int*)d_in[1];

    // ws layout (float units):
    //   [0] done (int) | [16..56) pn[40] | [64..74) ssqk | [80..90) cntk
    //   [96..1376) P_cnt[1280] (int) | [1536..6656) P_ssq[5120]
    //   [6720..) P_sum: 128*10*4*320 float4 (byte off 26880, 16B-aligned)
    float*  hdr   = (float*)d_ws;
    int*    done  = (int*)hdr;
    float*  pn    = hdr + 16;
    float*  ssqk  = hdr + 64;
    float*  cntk  = hdr + 80;
    int*    P_cnt = (int*)(hdr + 96);
    float*  P_ssq = hdr + 1536;
    float4* P_sum = (float4*)(hdr + 6720);

    hipMemsetAsync(done, 0, sizeof(int), stream);   // ticket init (ws poisoned)
    codi_fused<<<NBLK, NT1, 0, stream>>>(z4, labels, P_sum, P_ssq, P_cnt,
                                         pn, ssqk, cntk, done, (float*)d_out);
}

// Round 3
// 335.374 us; speedup vs baseline: 1.0053x; 1.0053x over previous
//
#include <hip/hip_runtime.h>

// Problem constants (fixed by setup_inputs)
#define B_SZ   8192
#define CH     5120          // C*H = 20*256
#define CH4    1280          // CH / 4 (float4 columns per row)
#define K_LAB  10
#define EPS    1e-8f
#define FLTMAX 3.402823466e38f

// Pass-1 tiling: 256 row-chunks x 4 col-chunks = 1024 blocks (4 per CU)
#define RC_N   256           // row chunks
#define ROWS   32            // rows per chunk (RC_N*ROWS == B_SZ)
#define CC_N   4             // col chunks
#define CCW    320           // float4 columns per col chunk (CC_N*CCW == CH4)
#define NT1    320           // 5 waves
#define NFOLD  (K_LAB * CC_N)           // 40 fold blocks (k, cc)

// loss = sum_{k: n_k>0} (SSQ_k - ||S_k||^2/n_k + n_k*CH*eps^2) / (n_k*CH)
// (2*eps cross-term cancels exactly: sum_{b in k}(z_b - mu_k) == 0)

__device__ __forceinline__ float4 sanitize(float4 v) {
    v.x = (v.x == v.x) ? fminf(fmaxf(v.x, -FLTMAX), FLTMAX) : 0.f;
    v.y = (v.y == v.y) ? fminf(fmaxf(v.y, -FLTMAX), FLTMAX) : 0.f;
    v.z = (v.z == v.z) ? fminf(fmaxf(v.z, -FLTMAX), FLTMAX) : 0.f;
    v.w = (v.w == v.w) ? fminf(fmaxf(v.w, -FLTMAX), FLTMAX) : 0.f;
    return v;
}

// ---------------------------------------------------------------------------
// Pass 1: stream z contiguously; predicated per-label accumulation in regs.
// P_sum layout [k][cc][rc][col]: writes stay coalesced (320 consecutive
// float4 per label), and pass-2's rc-fold becomes a sequential stream.
__global__ __launch_bounds__(NT1, 5) void codi_pass1(
    const float4* __restrict__ z4, const int* __restrict__ labels,
    float4* __restrict__ P_sum, float* __restrict__ P_ssq,
    int* __restrict__ P_cnt, int* __restrict__ done)
{
    const int tid = threadIdx.x;
    const int rc  = blockIdx.x >> 2;     // row-chunk
    const int cc  = blockIdx.x & 3;      // col-chunk

    __shared__ int   lab_s[ROWS];
    __shared__ float wssq[5][K_LAB];

    if (blockIdx.x == 0 && tid == 0) *done = 0;   // re-init ticket (poisoned ws)

    if (tid < ROWS) lab_s[tid] = labels[rc * ROWS + tid];
    __syncthreads();

    float4 sum[K_LAB];
    float  ssq[K_LAB];
    #pragma unroll
    for (int k = 0; k < K_LAB; ++k) {
        sum[k] = make_float4(0.f, 0.f, 0.f, 0.f);
        ssq[k] = 0.f;
    }

    // thread owns one float4 column; rows are contiguous -> pure streaming
    const float4* zp = z4 + (size_t)rc * ROWS * CH4 + cc * CCW + tid;

    for (int r = 0; r < ROWS; r += 8) {
        float4 v[8];
        #pragma unroll
        for (int u = 0; u < 8; ++u) v[u] = zp[(size_t)(r + u) * CH4];

        #pragma unroll
        for (int u = 0; u < 8; ++u) {
            // label is uniform across the block for this row -> scalarize
            const int lab = __builtin_amdgcn_readfirstlane(lab_s[r + u]);
            float4 t = sanitize(v[u]);
            float  q = fmaf(t.x, t.x, fmaf(t.y, t.y, fmaf(t.z, t.z, t.w * t.w)));
            #pragma unroll
            for (int k = 0; k < K_LAB; ++k) {
                const float w = (lab == k) ? 1.f : 0.f;   // scalar operand
                sum[k].x = fmaf(t.x, w, sum[k].x);
                sum[k].y = fmaf(t.y, w, sum[k].y);
                sum[k].z = fmaf(t.z, w, sum[k].z);
                sum[k].w = fmaf(t.w, w, sum[k].w);
                ssq[k]   = fmaf(q,   w, ssq[k]);
            }
        }
    }

    // per-label partial row-sums, [k][cc][rc][col]: coalesced 5 KB stores
    #pragma unroll
    for (int k = 0; k < K_LAB; ++k)
        P_sum[(((size_t)(k * CC_N + cc)) * RC_N + rc) * CCW + tid] = sum[k];

    // block-reduce ssq[k] -> P_ssq[(rc*4+cc)*10 + k]
    const int lane = tid & 63, wid = tid >> 6;
    #pragma unroll
    for (int k = 0; k < K_LAB; ++k) {
        float s = ssq[k];
        #pragma unroll
        for (int o = 32; o > 0; o >>= 1) s += __shfl_down(s, o, 64);
        if (lane == 0) wssq[wid][k] = s;
    }
    __syncthreads();
    if (tid < K_LAB)
        P_ssq[(rc * CC_N + cc) * K_LAB + tid] =
            wssq[0][tid] + wssq[1][tid] + wssq[2][tid] + wssq[3][tid] + wssq[4][tid];

    // per-chunk label counts (one writer: cc==0, wave 0, 10 ballots)
    if (cc == 0 && tid < 64) {
        const int lab = (tid < ROWS) ? lab_s[tid] : -1;
        #pragma unroll
        for (int k = 0; k < K_LAB; ++k) {
            unsigned long long m = __ballot(lab == k);
            if (tid == k) P_cnt[rc * K_LAB + k] = __popcll(m);
        }
    }
}

// ---------------------------------------------------------------------------
// Pass 2: 40 blocks (k, cc); each streams its 1.3 MB [rc][col] panel
// sequentially (L2/L3-hot), folds to ||S_k||^2 partials; fcc==0 blocks fold
// SSQ_k and n_k; last-ticket block finalizes the loss.
__global__ __launch_bounds__(NT1) void codi_pass2(
    const float4* __restrict__ P_sum, const float* __restrict__ P_ssq,
    const int* __restrict__ P_cnt, float* __restrict__ pn,
    float* __restrict__ ssqk, float* __restrict__ cntk,
    int* __restrict__ done, float* __restrict__ out)
{
    const int tid  = threadIdx.x;
    const int lane = tid & 63, wid = tid >> 6;
    const int fid  = blockIdx.x;         // 0..39
    const int fk   = fid >> 2, fcc = fid & 3;

    __shared__ float red_q[5], red_s[5];
    __shared__ int   red_n[5];
    __shared__ int   tkt;

    // col-sum over rc: block walks 256 x 5 KB sequentially
    const float4* p = P_sum + ((size_t)(fk * CC_N + fcc) * RC_N) * CCW + tid;
    float4 s4 = make_float4(0.f, 0.f, 0.f, 0.f);
    #pragma unroll 8
    for (int rc = 0; rc < RC_N; ++rc) {
        float4 v = p[(size_t)rc * CCW];
        s4.x += v.x; s4.y += v.y; s4.z += v.z; s4.w += v.w;
    }
    float q = fmaf(s4.x, s4.x, fmaf(s4.y, s4.y, fmaf(s4.z, s4.z, s4.w * s4.w)));
    #pragma unroll
    for (int o = 32; o > 0; o >>= 1) q += __shfl_down(q, o, 64);

    // SSQ_k and n_k folds (only the fcc==0 block of each k)
    float s2 = 0.f;
    int   n  = 0;
    if (fcc == 0) {
        for (int i = tid; i < RC_N * CC_N; i += NT1) s2 += P_ssq[i * K_LAB + fk];
        if (tid < RC_N) n = P_cnt[tid * K_LAB + fk];
    }
    #pragma unroll
    for (int o = 32; o > 0; o >>= 1) s2 += __shfl_down(s2, o, 64);
    #pragma unroll
    for (int o = 32; o > 0; o >>= 1) n += __shfl_down(n, o, 64);

    if (lane == 0) { red_q[wid] = q; red_s[wid] = s2; red_n[wid] = n; }
    __syncthreads();
    if (tid == 0) {
        pn[fid] = red_q[0] + red_q[1] + red_q[2] + red_q[3] + red_q[4];
        if (fcc == 0) {
            ssqk[fk] = red_s[0] + red_s[1] + red_s[2] + red_s[3] + red_s[4];
            cntk[fk] = (float)(red_n[0] + red_n[1] + red_n[2] + red_n[3] + red_n[4]);
        }
    }

    // ---------------- finalize: last block computes the loss
    __threadfence();
    __syncthreads();
    if (tid == 0) tkt = atomicAdd(done, 1);   // tickets 0..39
    __syncthreads();
    if (tkt == NFOLD - 1 && tid < 64) {
        float np4 = (tid < NFOLD) ? atomicAdd(&pn[tid], 0.f) : 0.f;   // coherent
        np4 += __shfl_down(np4, 2, 64);
        np4 += __shfl_down(np4, 1, 64);   // lane 4k holds sum over cc
        float s2v = (tid < K_LAB) ? atomicAdd(&ssqk[tid], 0.f) : 0.f;
        float nnv = (tid < K_LAB) ? atomicAdd(&cntk[tid], 0.f) : 0.f;
        float acc = 0.f;
        for (int k = 0; k < K_LAB; ++k) {
            float np = __shfl(np4, 4 * k, 64);
            float sk = __shfl(s2v, k, 64);
            float nk = __shfl(nnv, k, 64);
            if (nk > 0.f) {
                float sse = sk - np / nk + nk * (float)CH * (EPS * EPS);
                float mse = sse / (nk * (float)CH);
                if (mse == mse) acc += mse;    // nan_to_num(mse_k)
            }
        }
        if (tid == 0) out[0] = acc;
    }
}

// ---------------------------------------------------------------------------
extern "C" void kernel_launch(void* const* d_in, const int* in_sizes, int n_in,
                              void* d_out, int out_size, void* d_ws, size_t ws_size,
                              hipStream_t stream) {
    const float4* z4     = (const float4*)d_in[0];
    const int*    labels = (const int*)d_in[1];

    // ws layout (float units):
    //   [0] done (int) | [16..56) pn[40] | [64..74) ssqk | [80..90) cntk
    //   [96..2656) P_cnt[2560] (int) | [2688..12928) P_ssq[10240]
    //   [13056..) P_sum: 10*4*256*320 float4 (byte off 52224, 16B-aligned)
    float*  hdr   = (float*)d_ws;
    int*    done  = (int*)hdr;
    float*  pn    = hdr + 16;
    float*  ssqk  = hdr + 64;
    float*  cntk  = hdr + 80;
    int*    P_cnt = (int*)(hdr + 96);
    float*  P_ssq = hdr + 2688;
    float4* P_sum = (float4*)(hdr + 13056);

    codi_pass1<<<RC_N * CC_N, NT1, 0, stream>>>(z4, labels, P_sum, P_ssq, P_cnt, done);
    codi_pass2<<<NFOLD, NT1, 0, stream>>>(P_sum, P_ssq, P_cnt, pn, ssqk,
                                          cntk, done, (float*)d_out);
}

// Round 4
// 274.366 us; speedup vs baseline: 1.2288x; 1.2224x over previous
//
#include <hip/hip_runtime.h>

// Problem constants (fixed by setup_inputs)
#define B_SZ   8192
#define CH     5120          // C*H = 20*256
#define CH4    1280          // CH / 4 (float4 columns per row)
#define K_LAB  10
#define EPS    1e-8f
#define FLTMAX 3.402823466e38f

// Pass-1 tiling: 128 row-chunks x 4 col-chunks = 512 blocks (2 per CU)
#define RC_N   128           // row chunks
#define ROWS   64            // rows per chunk (RC_N*ROWS == B_SZ)
#define CC_N   4             // col chunks
#define CCW    320           // float4 columns per col chunk (CC_N*CCW == CH4)
#define NT1    320           // 5 waves
#define NFOLD  (K_LAB * CC_N)           // 40 fold blocks (k, cc)

// loss = sum_{k: n_k>0} (SSQ_k - ||S_k||^2/n_k + n_k*CH*eps^2) / (n_k*CH)
// (2*eps cross-term cancels exactly: sum_{b in k}(z_b - mu_k) == 0)

__device__ __forceinline__ float4 sanitize(float4 v) {
    v.x = (v.x == v.x) ? fminf(fmaxf(v.x, -FLTMAX), FLTMAX) : 0.f;
    v.y = (v.y == v.y) ? fminf(fmaxf(v.y, -FLTMAX), FLTMAX) : 0.f;
    v.z = (v.z == v.z) ? fminf(fmaxf(v.z, -FLTMAX), FLTMAX) : 0.f;
    v.w = (v.w == v.w) ? fminf(fmaxf(v.w, -FLTMAX), FLTMAX) : 0.f;
    return v;
}

// ---------------------------------------------------------------------------
// Pass 1: stream z contiguously. Label is block-uniform per row -> scalarize
// (readfirstlane) and accumulate via a uniform switch: 5 FMAs/row-element
// instead of 50 predicated ones. NO __launch_bounds__ min-waves: R3 showed
// (NT1,5) forces VGPR=48 and spills the 50-reg accumulator state to scratch
// (WRITE_SIZE 215 MB vs 26 MB of stores, 150 us @ 31% BW).
__global__ __launch_bounds__(NT1) void codi_pass1(
    const float4* __restrict__ z4, const int* __restrict__ labels,
    float4* __restrict__ P_sum, float* __restrict__ P_ssq,
    int* __restrict__ P_cnt, int* __restrict__ done)
{
    const int tid = threadIdx.x;
    const int rc  = blockIdx.x >> 2;     // row-chunk
    const int cc  = blockIdx.x & 3;      // col-chunk

    __shared__ int   lab_s[ROWS];
    __shared__ float wssq[5][K_LAB];

    if (blockIdx.x == 0 && tid == 0) *done = 0;   // re-init ticket (poisoned ws)

    if (tid < ROWS) lab_s[tid] = labels[rc * ROWS + tid];
    __syncthreads();

    float4 sum[K_LAB];
    float  ssq[K_LAB];
    #pragma unroll
    for (int k = 0; k < K_LAB; ++k) {
        sum[k] = make_float4(0.f, 0.f, 0.f, 0.f);
        ssq[k] = 0.f;
    }

    // thread owns one float4 column; rows are contiguous -> pure streaming
    const float4* zp = z4 + (size_t)rc * ROWS * CH4 + cc * CCW + tid;

    for (int r = 0; r < ROWS; r += 8) {
        float4 v[8];
        #pragma unroll
        for (int u = 0; u < 8; ++u) v[u] = zp[(size_t)(r + u) * CH4];

        #pragma unroll
        for (int u = 0; u < 8; ++u) {
            const int lab = __builtin_amdgcn_readfirstlane(lab_s[r + u]);
            float4 t = sanitize(v[u]);
            float  q = fmaf(t.x, t.x, fmaf(t.y, t.y, fmaf(t.z, t.z, t.w * t.w)));
            // wave-uniform branch (s_cbranch tree on SGPR): one 5-FMA body/row
            #define ACC(K) do { \
                sum[K].x += t.x; sum[K].y += t.y; \
                sum[K].z += t.z; sum[K].w += t.w; ssq[K] += q; } while (0)
            switch (lab) {
                case 0: ACC(0); break;  case 1: ACC(1); break;
                case 2: ACC(2); break;  case 3: ACC(3); break;
                case 4: ACC(4); break;  case 5: ACC(5); break;
                case 6: ACC(6); break;  case 7: ACC(7); break;
                case 8: ACC(8); break;  default: ACC(9); break;
            }
            #undef ACC
        }
    }

    // per-label partial row-sums, [k][cc][rc][col]: coalesced 5 KB stores,
    // and pass-2's rc-fold is a sequential stream (R3's transpose, proven)
    #pragma unroll
    for (int k = 0; k < K_LAB; ++k)
        P_sum[(((size_t)(k * CC_N + cc)) * RC_N + rc) * CCW + tid] = sum[k];

    // block-reduce ssq[k] -> P_ssq[(rc*4+cc)*10 + k]
    const int lane = tid & 63, wid = tid >> 6;
    #pragma unroll
    for (int k = 0; k < K_LAB; ++k) {
        float s = ssq[k];
        #pragma unroll
        for (int o = 32; o > 0; o >>= 1) s += __shfl_down(s, o, 64);
        if (lane == 0) wssq[wid][k] = s;
    }
    __syncthreads();
    if (tid < K_LAB)
        P_ssq[(rc * CC_N + cc) * K_LAB + tid] =
            wssq[0][tid] + wssq[1][tid] + wssq[2][tid] + wssq[3][tid] + wssq[4][tid];

    // per-chunk label counts (one writer: cc==0, wave 0, 10 ballots)
    if (cc == 0 && tid < 64) {
        const int lab = lab_s[tid];
        #pragma unroll
        for (int k = 0; k < K_LAB; ++k) {
            unsigned long long m = __ballot(lab == k);
            if (tid == k) P_cnt[rc * K_LAB + k] = __popcll(m);
        }
    }
}

// ---------------------------------------------------------------------------
// Pass 2: 40 blocks (k, cc); each streams its 655 KB [rc][col] panel
// sequentially (L2/L3-hot), folds to ||S_k||^2 partials; fcc==0 blocks fold
// SSQ_k and n_k; last-ticket block finalizes the loss.
__global__ __launch_bounds__(NT1) void codi_pass2(
    const float4* __restrict__ P_sum, const float* __restrict__ P_ssq,
    const int* __restrict__ P_cnt, float* __restrict__ pn,
    float* __restrict__ ssqk, float* __restrict__ cntk,
    int* __restrict__ done, float* __restrict__ out)
{
    const int tid  = threadIdx.x;
    const int lane = tid & 63, wid = tid >> 6;
    const int fid  = blockIdx.x;         // 0..39
    const int fk   = fid >> 2, fcc = fid & 3;

    __shared__ float red_q[5], red_s[5];
    __shared__ int   red_n[5];
    __shared__ int   tkt;

    // col-sum over rc: block walks 128 x 5 KB sequentially
    const float4* p = P_sum + ((size_t)(fk * CC_N + fcc) * RC_N) * CCW + tid;
    float4 s4 = make_float4(0.f, 0.f, 0.f, 0.f);
    #pragma unroll 8
    for (int rc = 0; rc < RC_N; ++rc) {
        float4 v = p[(size_t)rc * CCW];
        s4.x += v.x; s4.y += v.y; s4.z += v.z; s4.w += v.w;
    }
    float q = fmaf(s4.x, s4.x, fmaf(s4.y, s4.y, fmaf(s4.z, s4.z, s4.w * s4.w)));
    #pragma unroll
    for (int o = 32; o > 0; o >>= 1) q += __shfl_down(q, o, 64);

    // SSQ_k and n_k folds (only the fcc==0 block of each k)
    float s2 = 0.f;
    int   n  = 0;
    if (fcc == 0) {
        for (int i = tid; i < RC_N * CC_N; i += NT1) s2 += P_ssq[i * K_LAB + fk];
        if (tid < RC_N) n = P_cnt[tid * K_LAB + fk];
    }
    #pragma unroll
    for (int o = 32; o > 0; o >>= 1) s2 += __shfl_down(s2, o, 64);
    #pragma unroll
    for (int o = 32; o > 0; o >>= 1) n += __shfl_down(n, o, 64);

    if (lane == 0) { red_q[wid] = q; red_s[wid] = s2; red_n[wid] = n; }
    __syncthreads();
    if (tid == 0) {
        pn[fid] = red_q[0] + red_q[1] + red_q[2] + red_q[3] + red_q[4];
        if (fcc == 0) {
            ssqk[fk] = red_s[0] + red_s[1] + red_s[2] + red_s[3] + red_s[4];
            cntk[fk] = (float)(red_n[0] + red_n[1] + red_n[2] + red_n[3] + red_n[4]);
        }
    }

    // ---------------- finalize: last block computes the loss
    __threadfence();
    __syncthreads();
    if (tid == 0) tkt = atomicAdd(done, 1);   // tickets 0..39
    __syncthreads();
    if (tkt == NFOLD - 1 && tid < 64) {
        float np4 = (tid < NFOLD) ? atomicAdd(&pn[tid], 0.f) : 0.f;   // coherent
        np4 += __shfl_down(np4, 2, 64);
        np4 += __shfl_down(np4, 1, 64);   // lane 4k holds sum over cc
        float s2v = (tid < K_LAB) ? atomicAdd(&ssqk[tid], 0.f) : 0.f;
        float nnv = (tid < K_LAB) ? atomicAdd(&cntk[tid], 0.f) : 0.f;
        float acc = 0.f;
        for (int k = 0; k < K_LAB; ++k) {
            float np = __shfl(np4, 4 * k, 64);
            float sk = __shfl(s2v, k, 64);
            float nk = __shfl(nnv, k, 64);
            if (nk > 0.f) {
                float sse = sk - np / nk + nk * (float)CH * (EPS * EPS);
                float mse = sse / (nk * (float)CH);
                if (mse == mse) acc += mse;    // nan_to_num(mse_k)
            }
        }
        if (tid == 0) out[0] = acc;
    }
}

// ---------------------------------------------------------------------------
extern "C" void kernel_launch(void* const* d_in, const int* in_sizes, int n_in,
                              void* d_out, int out_size, void* d_ws, size_t ws_size,
                              hipStream_t stream) {
    const float4* z4     = (const float4*)d_in[0];
    const int*    labels = (const int*)d_in[1];

    // ws layout (float units):
    //   [0] done (int) | [16..56) pn[40] | [64..74) ssqk | [80..90) cntk
    //   [96..1376) P_cnt[1280] (int) | [1536..6656) P_ssq[5120]
    //   [6720..) P_sum: 10*4*128*320 float4 (byte off 26880, 16B-aligned)
    float*  hdr   = (float*)d_ws;
    int*    done  = (int*)hdr;
    float*  pn    = hdr + 16;
    float*  ssqk  = hdr + 64;
    float*  cntk  = hdr + 80;
    int*    P_cnt = (int*)(hdr + 96);
    float*  P_ssq = hdr + 1536;
    float4* P_sum = (float4*)(hdr + 6720);

    codi_pass1<<<RC_N * CC_N, NT1, 0, stream>>>(z4, labels, P_sum, P_ssq, P_cnt, done);
    codi_pass2<<<NFOLD, NT1, 0, stream>>>(P_sum, P_ssq, P_cnt, pn, ssqk,
                                          cntk, done, (float*)d_out);
}